// Round 8
// baseline (160.179 us; speedup 1.0000x reference)
//
#include <hip/hip_runtime.h>

// NearestEmbed (VQ argmin + gather), MI355X gfx950.  Round 8.
// x: (B=64, D=64, H=32, W=32) fp32 ; emb: (D=64, K=512) fp32
// out0: quant (B,D,H,W) fp32 ; out1: argmin (B,H,W) as fp32 values.
//
// R8 vs R7 (96us, VALUBusy 46%, FETCH/WRITE ideal): pure latency-hiding.
//  1. emb transposed into d_ws as [K][68] (64 col vals + ||e||^2 + 3 pad,
//     16B-aligned records): per-lane column reads become contiguous
//     global_load_dwordx4 -> 1 VMEM per 64 FMAs (was 1 per 16), manually
//     double-buffered via two NAMED f4s (no arrays -> no alloca, R4/5/6
//     lesson). Prefetch of dt+1 at dt=15 lands on the e2/pad words: in-record.
//  2. 2x TLP: code-sets split across wave pairs (4 waves = 2 row-groups x
//     2 K-halves), 2048 blocks -> 8 waves/SIMD launched (VGPR-capped ~6).
//     640B LDS merge; K-half 0 wins score ties -> numpy first-index argmin.
// Floor: 2.147e9 lane-FMA /(1024 SIMD*32 lanes)/2.4GHz = 27.3 us.

constexpr int D   = 64;
constexpr int K   = 512;
constexpr int HW  = 1024;     // 32*32
constexpr int REC = 68;       // ws record stride in floats (272 B, 16B-aligned)

typedef float f4 __attribute__((ext_vector_type(4)));

__global__ __launch_bounds__(256) void emb_transpose_kernel(
    const float* __restrict__ emb, float* __restrict__ ws)
{
    const int k = blockIdx.x * 256 + threadIdx.x;   // 2 blocks x 256 = 512
    if (k < K) {
        float s = 0.f;
        #pragma unroll 16
        for (int d = 0; d < D; ++d) {
            float v = emb[d * K + k];               // coalesced across lanes
            ws[k * REC + d] = v;
            s = fmaf(v, v, s);
        }
        ws[k * REC + 64] = s;                       // ||e_k||^2
    }
}

__global__ __launch_bounds__(256, 6) void vq_argmin_kernel(
    const float* __restrict__ x,
    const float* __restrict__ ws,        // [K][REC] transposed emb + e2
    float* __restrict__ out_q,
    float* __restrict__ out_idx)
{
    __shared__ float mbs[2][32];
    __shared__ int   mis[2][32];
    __shared__ int   kfin[32];

    const int tid  = threadIdx.x;
    const int lane = tid & 63;
    const int wv   = __builtin_amdgcn_readfirstlane(tid >> 6);  // 0..3
    const int wrow = wv & 1;          // row group within block
    const int wcs  = wv >> 1;         // K-half 0/1
    const int r0   = blockIdx.x * 32 + wrow * 16;   // first row of this wave
    const int b    = r0 >> 10;                      // batch (32 | 1024: no straddle)
    const int n0   = r0 & 1023;

    const float* xb = x + (size_t)b * D * HW + n0;  // wave-uniform -> s_load path

    float best[16];
    int   bidx[16];
    #pragma unroll
    for (int r = 0; r < 16; ++r) { best[r] = 3.4e38f; bidx[r] = 0; }

    for (int cs = 0; cs < 4; ++cs) {                // this wave's 4 code-sets
        const int kc = (wcs * 4 + cs) * 64 + lane;  // candidate code
        const float* cb = ws + kc * REC;            // per-lane, 16B-aligned

        float acc[16];
        #pragma unroll
        for (int r = 0; r < 16; ++r) acc[r] = 0.f;

        f4 evc = *(const f4*)cb;                    // named f4: stays in VGPRs
        for (int dt = 0; dt < 16; ++dt) {
            f4 evn = *(const f4*)(cb + (dt + 1) * 4);   // prefetch (dt=15 -> e2/pad, in-record)
            #pragma unroll
            for (int j = 0; j < 4; ++j) {
                const int d = dt * 4 + j;
                const float ev = evc[j];                // const idx into ext_vector
                const float* xp = xb + (size_t)d * HW;  // uniform -> s_load_dwordx16
                #pragma unroll
                for (int r = 0; r < 16; ++r)
                    acc[r] = fmaf(ev, xp[r], acc[r]);   // SGPR x VGPR fma
            }
            evc = evn;
        }

        const float e2 = cb[64];                    // precomputed ||e||^2
        #pragma unroll
        for (int r = 0; r < 16; ++r) {
            float s = fmaf(-2.f, acc[r], e2);       // same form as reference
            if (s < best[r]) { best[r] = s; bidx[r] = kc; }  // strict <: cs ascends
        }
    }

    // --- cross-lane argmin per row: butterfly, tie -> lower index ---
    #pragma unroll
    for (int r = 0; r < 16; ++r) {
        float bs = best[r]; int bi = bidx[r];
        #pragma unroll
        for (int off = 32; off >= 1; off >>= 1) {
            float os = __shfl_xor(bs, off);
            int   oi = __shfl_xor(bi, off);
            if (os < bs || (os == bs && oi < bi)) { bs = os; bi = oi; }
        }
        best[r] = bs; bidx[r] = bi;
    }

    // --- lane-select row (lane&15)'s result (cndmask chain, no dyn index) ---
    const int rr = lane & 15;
    float bs = best[0]; int bi = bidx[0];
    #pragma unroll
    for (int r = 1; r < 16; ++r)
        if (rr == r) { bs = best[r]; bi = bidx[r]; }

    if (lane < 16) { mbs[wcs][wrow * 16 + lane] = bs; mis[wcs][wrow * 16 + lane] = bi; }
    __syncthreads();

    // --- merge K-halves; half 0 (lower k) wins ties; write idx ---
    const int rb0 = blockIdx.x * 32;                // block row base
    if (tid < 32) {
        float b0 = mbs[0][tid]; int i0 = mis[0][tid];
        float b1 = mbs[1][tid]; int i1 = mis[1][tid];
        int kq = (b1 < b0) ? i1 : i0;
        kfin[tid] = kq;
        __builtin_nontemporal_store((float)kq, &out_idx[rb0 + tid]);
    }
    __syncthreads();

    // --- epilogue: quant gather from ws (L1-hot, contiguous records) ---
    const int bb  = rb0 >> 10;
    const int nn0 = rb0 & 1023;
    const int row   = tid & 31;
    const int dslot = tid >> 5;                     // 0..7
    const float* cq = ws + kfin[row] * REC;
    float* oqb = out_q + (size_t)bb * D * HW + nn0 + row;
    #pragma unroll
    for (int jj = 0; jj < 8; ++jj) {
        const int d = jj * 8 + dslot;
        // stores: 32 consecutive rows per (d) -> 128B segments, nontemporal
        __builtin_nontemporal_store(cq[d], &oqb[(size_t)d * HW]);
    }
}

extern "C" void kernel_launch(void* const* d_in, const int* in_sizes, int n_in,
                              void* d_out, int out_size, void* d_ws, size_t ws_size,
                              hipStream_t stream)
{
    const float* x   = (const float*)d_in[0];   // 4194304 floats
    const float* emb = (const float*)d_in[1];   // 32768 floats

    float* out_q   = (float*)d_out;                     // 4194304 floats
    float* out_idx = out_q + (size_t)64 * 64 * 1024;    // 65536 floats
    float* ws      = (float*)d_ws;                      // needs 512*68*4 = 139264 B

    // 1) transpose emb -> ws [K][68] with ||e||^2 (runs every call: harness
    //    re-poisons ws before each timed launch).
    emb_transpose_kernel<<<2, 256, 0, stream>>>(emb, ws);

    // 2) main scan: 65536 rows / 32 rows-per-block = 2048 blocks of 256
    //    (2 row-groups x 2 K-halves per block) -> 8 waves/SIMD launched.
    vq_argmin_kernel<<<2048, 256, 0, stream>>>(x, ws, out_q, out_idx);
}